// Round 9
// baseline (177.294 us; speedup 1.0000x reference)
//
#include <hip/hip_runtime.h>

typedef unsigned short ushort_t;
typedef __attribute__((ext_vector_type(8))) short shortx8;
typedef __attribute__((ext_vector_type(4))) float floatx4;
typedef __attribute__((ext_vector_type(2))) float floatx2;

#define NS 0.1f

__device__ __forceinline__ ushort_t f2bf_rne(float f) {
  union { float f; unsigned int u; } v; v.f = f;
  unsigned int r = v.u + 0x7FFFu + ((v.u >> 16) & 1u);
  return (ushort_t)(r >> 16);
}
// pack two f32 -> bf16x2 (round-half-up) in one v_perm: low16=bf(a), high16=bf(b)
__device__ __forceinline__ unsigned int pk2bf(float a, float b) {
  union { float f; unsigned int u; } x, y; x.f = a; y.f = b;
  return __builtin_amdgcn_perm(y.u + 0x8000u, x.u + 0x8000u, 0x07060302u);
}
// hardware packed f32->bf16 (RNE), 1 instr for 2 elems
__device__ __forceinline__ unsigned int cvtpk_bf16(float a, float b) {
  unsigned int r;
  asm("v_cvt_pk_bf16_f32 %0, %1, %2" : "=v"(r) : "v"(a), "v"(b));
  return r;
}
__device__ __forceinline__ ushort_t f2bf_rhu(float f) {
  union { float f; unsigned int u; } v; v.f = f;
  return (ushort_t)((v.u + 0x8000u) >> 16);
}
__device__ __forceinline__ float lk(float x) { return fmaxf(x, NS * x); }
__device__ __forceinline__ floatx2 lk2(floatx2 v) {
  return __builtin_elementwise_max(v, v * (floatx2){NS, NS});
}

// 16-lane-row full butterfly sum on the VALU pipe (DPP), zero LDS ops.
__device__ __forceinline__ float row16_sum(float x) {
  int t;
  t = __builtin_amdgcn_update_dpp(0, __builtin_bit_cast(int, x), 0x128, 0xF, 0xF, true); // row_ror:8
  x += __builtin_bit_cast(float, t);
  t = __builtin_amdgcn_update_dpp(0, __builtin_bit_cast(int, x), 0x124, 0xF, 0xF, true); // row_ror:4
  x += __builtin_bit_cast(float, t);
  t = __builtin_amdgcn_update_dpp(0, __builtin_bit_cast(int, x), 0x4E, 0xF, 0xF, true);  // quad xor2
  x += __builtin_bit_cast(float, t);
  t = __builtin_amdgcn_update_dpp(0, __builtin_bit_cast(int, x), 0xB1, 0xF, 0xF, true);  // quad xor1
  x += __builtin_bit_cast(float, t);
  return x;
}

// fragment-linear weight layout: element e = f*8+j, f = (s*NT + t)*64 + lane,
// value = W[k = s*32 + (lane>>4)*8 + j][n = t*16 + (lane&15)]  (W is KxN row-major)
__global__ __launch_bounds__(256) void prep_w(
    const float* __restrict__ W_e1, const float* __restrict__ W_e2,
    const float* __restrict__ W_h1, const float* __restrict__ W_h2,
    ushort_t* __restrict__ wijf, ushort_t* __restrict__ we2f,
    ushort_t* __restrict__ wh1f, ushort_t* __restrict__ wh2f) {
  int e = blockIdx.x * 256 + threadIdx.x;
  int which, le;
  if (e < 32768) { which = 0; le = e; }
  else if (e < 49152) { which = 1; le = e - 32768; }
  else if (e < 81920) { which = 2; le = e - 49152; }
  else { which = 3; le = e - 81920; }
  const int NT = (which == 0) ? 16 : 8;
  int f = le >> 3, j = le & 7;
  int lane = f & 63, ft = f >> 6;
  int t = ft % NT, s = ft / NT;
  int n = t * 16 + (lane & 15), k = s * 32 + (lane >> 4) * 8 + j;
  float v; ushort_t* d;
  if (which == 0) { v = (n < 128) ? W_e1[k * 128 + n] : W_e1[(128 + k) * 128 + (n - 128)]; d = wijf; }
  else if (which == 1) { v = W_e2[k * 128 + n]; d = we2f; }
  else if (which == 2) { v = W_h1[k * 128 + n]; d = wh1f; }
  else { v = W_h2[k * 128 + n]; d = wh2f; }
  d[le] = f2bf_rne(v);
}

// proj epilogue store: ti plain [m][n<128]; tj fragment-linear for the edge kernel:
// tjf[(((b*4 + s)*256 + j)*4 + lg)*8 + j8] = tj[j][k], k = s*32+lg*8+j8
__device__ __forceinline__ void proj_store(float v, int m, int n,
                                           float* __restrict__ ti, float* __restrict__ tjf) {
  if (n < 128) {
    ti[(size_t)m * 128 + n] = v;
  } else {
    int k = n - 128, b = m >> 8, j = m & 255;
    int s = k >> 5, lg2 = (k >> 3) & 3, j8 = k & 7;
    tjf[((((size_t)(b * 4 + s)) * 256 + j) * 4 + lg2) * 8 + j8] = v;
  }
}

// ---------------- h0 = leaky(fres @ W_emb) fused with proj [ti|tj] = h0 @ Wij ----------------
// 8 rows/block, 256 blocks. MFMA A rows 8-15 are stale LDS; A-row m only affects
// output row m, so all stores guarded to local row < 8.
__global__ __launch_bounds__(256) void h0_proj(
    const float* __restrict__ fres, const float* __restrict__ Wemb,
    const ushort_t* __restrict__ wijf, float* __restrict__ h_out,
    float* __restrict__ ti, float* __restrict__ tjf) {
  const int m0 = blockIdx.x * 8;
  const int tid = threadIdx.x;
  const int w = tid >> 6, lane = tid & 63, l16 = lane & 15, lg = lane >> 4;
  __shared__ __align__(16) ushort_t sH[16][136];   // rows 8-15 stale (never stored from)
  {
    const int row = tid >> 5, c0 = (tid & 31) * 4;
    const float* fr = fres + (size_t)(m0 + row) * 20;
    float a[4] = {0, 0, 0, 0};
    for (int k = 0; k < 20; ++k) {
      float fv = fr[k];
      float4 w0 = *(const float4*)(Wemb + k * 128 + c0);
      a[0] += fv * w0.x; a[1] += fv * w0.y; a[2] += fv * w0.z; a[3] += fv * w0.w;
    }
#pragma unroll
    for (int x = 0; x < 4; ++x) a[x] = lk(a[x]);
    float* ho = h_out + (size_t)(m0 + row) * 128 + c0;
    *(float4*)ho = (float4){a[0], a[1], a[2], a[3]};
    unsigned int* sh = (unsigned int*)&sH[row][c0];
    sh[0] = pk2bf(a[0], a[1]); sh[1] = pk2bf(a[2], a[3]);
  }
  __syncthreads();
  floatx4 ap[4];
#pragma unroll
  for (int q = 0; q < 4; ++q) ap[q] = (floatx4){0.f, 0.f, 0.f, 0.f};
  const shortx8* Wp = (const shortx8*)wijf;
#pragma unroll
  for (int s = 0; s < 4; ++s) {
    shortx8 af = *(const shortx8*)&sH[l16][s * 32 + lg * 8];
#pragma unroll
    for (int q = 0; q < 4; ++q)
      ap[q] = __builtin_amdgcn_mfma_f32_16x16x32_bf16(af, Wp[(s * 16 + 4 * w + q) * 64 + lane], ap[q], 0, 0, 0);
  }
#pragma unroll
  for (int q = 0; q < 4; ++q) {
    const int n = (4 * w + q) * 16 + l16;
#pragma unroll
    for (int r = 0; r < 4; ++r) {
      const int rl = lg * 4 + r;
      if (rl < 8) proj_store(ap[q][r], m0 + rl, n, ti, tjf);
    }
  }
}

// ---------------- edge_node v10: edge (both ch sequential) + fused 2-row node MLP ----------------
// One block per (b, i-pair). ch=0,1 processed sequentially reusing acc regs; full mp
// completes in-block -> node MLP (u -> h' -> proj) runs in the tail. ti/tjf double-
// buffered across iterations (read ti_in/tjf_in, write ti_out/tjf_out) to avoid the
// cross-block overwrite race the separate node launch used to prevent.
__global__ __launch_bounds__(256, 2) void edge_node(
    const float* __restrict__ ti_in, const float* __restrict__ tjf_in,
    const float* __restrict__ coords, const ushort_t* __restrict__ we2f,
    const float* __restrict__ W_e1, const float* __restrict__ b_e1,
    const float* __restrict__ b_e2, const float* __restrict__ W_inf,
    const float* __restrict__ b_inf,
    const float* __restrict__ h_in, const ushort_t* __restrict__ wh1f,
    const float* __restrict__ b_h1, const ushort_t* __restrict__ wh2f,
    const float* __restrict__ b_h2, const ushort_t* __restrict__ wijf,
    float* __restrict__ h_out, float* __restrict__ ti_out,
    float* __restrict__ tjf_out, const int do_proj) {
  const int blk = blockIdx.x;                 // XCD-major: b in low 3 bits (1024 % 8 == 0)
  const int b = blk & 7;
  const int ip = blk >> 3;                    // 0..127
  const int i0 = ip * 2;
  const int tid = threadIdx.x;
  const int w = tid >> 6, lane = tid & 63, l16 = lane & 15, lg = lane >> 4;

  __shared__ __align__(16) ushort_t sW[16384];   // 32 KB We2 fragment-linear
  __shared__ __align__(16) float sTiP[2][128];
  __shared__ __align__(16) float sWd[128];
  __shared__ __align__(16) float sD2[2][256];
  __shared__ __align__(16) float sMp[2][4][128];
  __shared__ __align__(16) float sMpF[2][128];
  __shared__ __align__(16) ushort_t sA[16][264];  // node MLP staging (rows 2-15 stale)
  __shared__ __align__(16) ushort_t sU[16][136];
  __shared__ __align__(16) ushort_t sHp[16][136];

  {
    // direct global->LDS staging: dest = wave-uniform base + lane*16 (linear)
    const int wbase = tid & ~63;
#pragma unroll
    for (int r = 0; r < 8; ++r) {
      const ushort_t* g = we2f + (size_t)(r * 256 + tid) * 8;
      ushort_t* l = (ushort_t*)sW + (size_t)(r * 256 + wbase) * 8;
      __builtin_amdgcn_global_load_lds(g, l, 16, 0, 0);
    }
  }
  if (tid < 128) {
    sTiP[0][tid] = ti_in[(size_t)(b * 256 + i0) * 128 + tid] + b_e1[tid];
    sWd[tid] = W_e1[256 * 128 + tid];
  } else {
    const int t2 = tid - 128;
    sTiP[1][t2] = ti_in[(size_t)(b * 256 + i0 + 1) * 128 + t2] + b_e1[t2];
  }
#pragma unroll
  for (int e = 0; e < 2; ++e) {
    const int idx = e * 256 + tid;
    const int ii = idx >> 8, jv = idx & 255;
    const int iv = i0 + ii;
    float dx = coords[(size_t)(b * 256 + iv) * 3 + 0] - coords[(size_t)(b * 256 + jv) * 3 + 0];
    float dy = coords[(size_t)(b * 256 + iv) * 3 + 1] - coords[(size_t)(b * 256 + jv) * 3 + 1];
    float dz = coords[(size_t)(b * 256 + iv) * 3 + 2] - coords[(size_t)(b * 256 + jv) * 3 + 2];
    sD2[ii][jv] = dx * dx + dy * dy + dz * dz;
  }

  float bv8[8], winfv[8];
#pragma unroll
  for (int t = 0; t < 8; ++t) {
    bv8[t] = b_e2[t * 16 + l16];
    winfv[t] = W_inf[t * 16 + l16];
  }
  const float binf = b_inf[0];
  __syncthreads();

  const shortx8* sWf = (const shortx8*)sW;

  for (int ch = 0; ch < 2; ++ch) {
    floatx4 acc[2][2][8];
#pragma unroll
    for (int t = 0; t < 8; ++t) {
      floatx4 v = (floatx4){bv8[t], bv8[t], bv8[t], bv8[t]};
      acc[0][0][t] = v; acc[0][1][t] = v; acc[1][0][t] = v; acc[1][1][t] = v;
    }
    float d2a[2][2];
#pragma unroll
    for (int ii = 0; ii < 2; ++ii)
#pragma unroll
      for (int c = 0; c < 2; ++c)
        d2a[ii][c] = sD2[ii][ch * 128 + c * 64 + w * 16 + l16];

#pragma unroll
    for (int s = 0; s < 4; ++s) {
      const int k0 = s * 32 + lg * 8;
      floatx2 w2[4];
#pragma unroll
      for (int x = 0; x < 4; ++x) w2[x] = *(const floatx2*)&sWd[k0 + 2 * x];
      shortx8 af[2][2];
#pragma unroll
      for (int c = 0; c < 2; ++c) {
        const int jr = ch * 128 + c * 64 + w * 16 + l16;   // j row (shared by both i)
        const float* tb = tjf_in + (((size_t)(b * 4 + s) * 256 + jr) * 4 + lg) * 8;
        float4 t0 = *(const float4*)tb;
        float4 t1 = *(const float4*)(tb + 4);
#pragma unroll
        for (int ii = 0; ii < 2; ++ii) {
          floatx2 p0 = *(const floatx2*)&sTiP[ii][k0 + 0];
          floatx2 p1 = *(const floatx2*)&sTiP[ii][k0 + 2];
          floatx2 p2v = *(const floatx2*)&sTiP[ii][k0 + 4];
          floatx2 p3 = *(const floatx2*)&sTiP[ii][k0 + 6];
          const floatx2 d2v = (floatx2){d2a[ii][c], d2a[ii][c]};
          floatx2 l0 = lk2((floatx2){t0.x, t0.y} + (p0 + d2v * w2[0]));
          floatx2 l1 = lk2((floatx2){t0.z, t0.w} + (p1 + d2v * w2[1]));
          floatx2 l2 = lk2((floatx2){t1.x, t1.y} + (p2v + d2v * w2[2]));
          floatx2 l3 = lk2((floatx2){t1.z, t1.w} + (p3 + d2v * w2[3]));
          union { shortx8 s8; unsigned int u[4]; } A;
          A.u[0] = cvtpk_bf16(l0.x, l0.y); A.u[1] = cvtpk_bf16(l1.x, l1.y);
          A.u[2] = cvtpk_bf16(l2.x, l2.y); A.u[3] = cvtpk_bf16(l3.x, l3.y);
          af[ii][c] = A.s8;
        }
      }
#pragma unroll
      for (int tg = 0; tg < 2; ++tg) {
        shortx8 b0 = sWf[(s * 8 + tg * 4 + 0) * 64 + lane];
        shortx8 b1 = sWf[(s * 8 + tg * 4 + 1) * 64 + lane];
        shortx8 b2 = sWf[(s * 8 + tg * 4 + 2) * 64 + lane];
        shortx8 b3 = sWf[(s * 8 + tg * 4 + 3) * 64 + lane];
        __builtin_amdgcn_s_setprio(1);
#pragma unroll
        for (int ii = 0; ii < 2; ++ii)
#pragma unroll
          for (int c = 0; c < 2; ++c) {
            acc[ii][c][tg * 4 + 0] = __builtin_amdgcn_mfma_f32_16x16x32_bf16(af[ii][c], b0, acc[ii][c][tg * 4 + 0], 0, 0, 0);
            acc[ii][c][tg * 4 + 1] = __builtin_amdgcn_mfma_f32_16x16x32_bf16(af[ii][c], b1, acc[ii][c][tg * 4 + 1], 0, 0, 0);
            acc[ii][c][tg * 4 + 2] = __builtin_amdgcn_mfma_f32_16x16x32_bf16(af[ii][c], b2, acc[ii][c][tg * 4 + 2], 0, 0, 0);
            acc[ii][c][tg * 4 + 3] = __builtin_amdgcn_mfma_f32_16x16x32_bf16(af[ii][c], b3, acc[ii][c][tg * 4 + 3], 0, 0, 0);
          }
        __builtin_amdgcn_s_setprio(0);
      }
    }

    // epilogue per i: leaky, gate, masked weighted reduction (DPP row-reduce)
#pragma unroll
    for (int ii = 0; ii < 2; ++ii) {
      const int i = i0 + ii;
      float mpacc[8];
#pragma unroll
      for (int t = 0; t < 8; ++t) mpacc[t] = 0.f;
#pragma unroll
      for (int c = 0; c < 2; ++c) {
#pragma unroll
        for (int t = 0; t < 8; ++t) {
          floatx2 v0 = lk2((floatx2){acc[ii][c][t][0], acc[ii][c][t][1]});
          floatx2 v1 = lk2((floatx2){acc[ii][c][t][2], acc[ii][c][t][3]});
          acc[ii][c][t][0] = v0.x; acc[ii][c][t][1] = v0.y;
          acc[ii][c][t][2] = v1.x; acc[ii][c][t][3] = v1.y;
        }
#pragma unroll
        for (int r = 0; r < 4; ++r) {
          float sum = 0.f;
#pragma unroll
          for (int t = 0; t < 8; ++t) sum += acc[ii][c][t][r] * winfv[t];
          sum = row16_sum(sum);
          const int jg = ch * 128 + c * 64 + w * 16 + lg * 4 + r;
          float x = sum + binf;
          float e = __builtin_amdgcn_rcpf(1.f + __expf(-x));
          if (jg == i) e = 0.f;
#pragma unroll
          for (int t = 0; t < 8; ++t) mpacc[t] += acc[ii][c][t][r] * e;
        }
      }
#pragma unroll
      for (int t = 0; t < 8; ++t) {
        mpacc[t] += __shfl_xor(mpacc[t], 16);
        mpacc[t] += __shfl_xor(mpacc[t], 32);
      }
      if (lg == 0) {
        if (ch == 0) {
#pragma unroll
          for (int t = 0; t < 8; ++t) sMp[ii][w][t * 16 + l16] = mpacc[t];
        } else {
#pragma unroll
          for (int t = 0; t < 8; ++t) sMp[ii][w][t * 16 + l16] += mpacc[t];
        }
      }
    }
  }
  __syncthreads();
  // final mp for the block's two rows
  {
    const int ii = tid >> 7, col = tid & 127;
    sMpF[ii][col] = sMp[ii][0][col] + sMp[ii][1][col] + sMp[ii][2][col] + sMp[ii][3][col];
  }
  __syncthreads();

  // -------- fused node MLP for rows i0, i0+1 (stale A rows 2-15, stores guarded) --------
  if (tid < 64) {
    const int row = tid >> 5, c0 = (tid & 31) * 8;
    unsigned int* dst = (unsigned int*)&sA[row][c0];
    if (c0 < 128) {
      const float* src = h_in + (size_t)(b * 256 + i0 + row) * 128 + c0;
#pragma unroll
      for (int x = 0; x < 4; ++x) dst[x] = pk2bf(src[2 * x], src[2 * x + 1]);
    } else {
      const float* s0 = &sMpF[row][c0 - 128];
#pragma unroll
      for (int x = 0; x < 4; ++x) dst[x] = pk2bf(s0[2 * x], s0[2 * x + 1]);
    }
  }
  __syncthreads();
  // u = leaky(hm @ W_h1 + b_h1), tiles {2w, 2w+1}
  floatx4 au[2];
#pragma unroll
  for (int q = 0; q < 2; ++q) { float bv = b_h1[(2 * w + q) * 16 + l16]; au[q] = (floatx4){bv, bv, bv, bv}; }
  const shortx8* W1 = (const shortx8*)wh1f;
#pragma unroll
  for (int s = 0; s < 8; ++s) {
    shortx8 af = *(const shortx8*)&sA[l16][s * 32 + lg * 8];
#pragma unroll
    for (int q = 0; q < 2; ++q)
      au[q] = __builtin_amdgcn_mfma_f32_16x16x32_bf16(af, W1[(s * 8 + 2 * w + q) * 64 + lane], au[q], 0, 0, 0);
  }
#pragma unroll
  for (int q = 0; q < 2; ++q)
#pragma unroll
    for (int r = 0; r < 4; ++r) {
      const int rl = lg * 4 + r;
      if (rl < 2) sU[rl][(2 * w + q) * 16 + l16] = f2bf_rhu(lk(au[q][r]));
    }
  __syncthreads();
  // h' = u @ W_h2 + b_h2 + h
  floatx4 ah[2];
#pragma unroll
  for (int q = 0; q < 2; ++q) { float bv = b_h2[(2 * w + q) * 16 + l16]; ah[q] = (floatx4){bv, bv, bv, bv}; }
  const shortx8* W2 = (const shortx8*)wh2f;
#pragma unroll
  for (int s = 0; s < 4; ++s) {
    shortx8 af = *(const shortx8*)&sU[l16][s * 32 + lg * 8];
#pragma unroll
    for (int q = 0; q < 2; ++q)
      ah[q] = __builtin_amdgcn_mfma_f32_16x16x32_bf16(af, W2[(s * 8 + 2 * w + q) * 64 + lane], ah[q], 0, 0, 0);
  }
#pragma unroll
  for (int q = 0; q < 2; ++q) {
    const int n = (2 * w + q) * 16 + l16;
#pragma unroll
    for (int r = 0; r < 4; ++r) {
      const int rl = lg * 4 + r;
      if (rl < 2) {
        const size_t m = (size_t)(b * 256 + i0 + rl);
        float v = ah[q][r] + h_in[m * 128 + n];
        h_out[m * 128 + n] = v;
        sHp[rl][n] = f2bf_rhu(v);
      }
    }
  }
  if (!do_proj) return;
  __syncthreads();
  // [ti|tj] = h' @ Wij, tiles {4w..4w+3}
  floatx4 ap[4];
#pragma unroll
  for (int q = 0; q < 4; ++q) ap[q] = (floatx4){0.f, 0.f, 0.f, 0.f};
  const shortx8* Wp = (const shortx8*)wijf;
#pragma unroll
  for (int s = 0; s < 4; ++s) {
    shortx8 af = *(const shortx8*)&sHp[l16][s * 32 + lg * 8];
#pragma unroll
    for (int q = 0; q < 4; ++q)
      ap[q] = __builtin_amdgcn_mfma_f32_16x16x32_bf16(af, Wp[(s * 16 + 4 * w + q) * 64 + lane], ap[q], 0, 0, 0);
  }
#pragma unroll
  for (int q = 0; q < 4; ++q) {
    const int n = (4 * w + q) * 16 + l16;
#pragma unroll
    for (int r = 0; r < 4; ++r) {
      const int rl = lg * 4 + r;
      if (rl < 2) proj_store(ap[q][r], b * 256 + i0 + rl, n, ti_out, tjf_out);
    }
  }
}

extern "C" void kernel_launch(void* const* d_in, const int* in_sizes, int n_in,
                              void* d_out, int out_size, void* d_ws, size_t ws_size,
                              hipStream_t stream) {
  const float* fres   = (const float*)d_in[0];
  const float* coords = (const float*)d_in[1];
  const float* W_emb  = (const float*)d_in[2];
  const float* W_e1   = (const float*)d_in[3];
  const float* b_e1   = (const float*)d_in[4];
  const float* W_e2   = (const float*)d_in[5];
  const float* b_e2   = (const float*)d_in[6];
  const float* W_inf  = (const float*)d_in[7];
  const float* b_inf  = (const float*)d_in[8];
  const float* W_h1   = (const float*)d_in[9];
  const float* b_h1   = (const float*)d_in[10];
  const float* W_h2   = (const float*)d_in[11];
  const float* b_h2   = (const float*)d_in[12];
  float* out = (float*)d_out;

  char* ws = (char*)d_ws;
  float* hA   = (float*)(ws + (0 << 20));
  float* hB   = (float*)(ws + (1 << 20));
  float* ti0  = (float*)(ws + (2 << 20));
  float* tjf0 = (float*)(ws + (3 << 20));
  float* ti1  = (float*)(ws + (4 << 20));
  float* tjf1 = (float*)(ws + (5 << 20));
  ushort_t* wijf = (ushort_t*)(ws + (6 << 20));
  ushort_t* we2f = wijf + 32768;
  ushort_t* wh1f = we2f + 16384;
  ushort_t* wh2f = wh1f + 32768;

  prep_w<<<384, 256, 0, stream>>>(W_e1, W_e2, W_h1, W_h2, wijf, we2f, wh1f, wh2f);
  h0_proj<<<256, 256, 0, stream>>>(fres, W_emb, wijf, hA, ti0, tjf0);

  edge_node<<<1024, 256, 0, stream>>>(ti0, tjf0, coords, we2f, W_e1, b_e1, b_e2, W_inf, b_inf,
                                      hA, wh1f, b_h1, wh2f, b_h2, wijf, hB, ti1, tjf1, 1);
  edge_node<<<1024, 256, 0, stream>>>(ti1, tjf1, coords, we2f, W_e1, b_e1, b_e2, W_inf, b_inf,
                                      hB, wh1f, b_h1, wh2f, b_h2, wijf, out, ti0, tjf0, 0);
}

// Round 11
// 162.704 us; speedup vs baseline: 1.0897x; 1.0897x over previous
//
#include <hip/hip_runtime.h>

typedef unsigned short ushort_t;
typedef __attribute__((ext_vector_type(8))) short shortx8;
typedef __attribute__((ext_vector_type(4))) float floatx4;
typedef __attribute__((ext_vector_type(2))) float floatx2;

#define NS 0.1f

__device__ __forceinline__ ushort_t f2bf_rne(float f) {
  union { float f; unsigned int u; } v; v.f = f;
  unsigned int r = v.u + 0x7FFFu + ((v.u >> 16) & 1u);
  return (ushort_t)(r >> 16);
}
// pack two f32 -> bf16x2 (round-half-up) in one v_perm: low16=bf(a), high16=bf(b)
__device__ __forceinline__ unsigned int pk2bf(float a, float b) {
  union { float f; unsigned int u; } x, y; x.f = a; y.f = b;
  return __builtin_amdgcn_perm(y.u + 0x8000u, x.u + 0x8000u, 0x07060302u);
}
// hardware packed f32->bf16 (RNE), 1 instr for 2 elems
__device__ __forceinline__ unsigned int cvtpk_bf16(float a, float b) {
  unsigned int r;
  asm("v_cvt_pk_bf16_f32 %0, %1, %2" : "=v"(r) : "v"(a), "v"(b));
  return r;
}
__device__ __forceinline__ ushort_t f2bf_rhu(float f) {
  union { float f; unsigned int u; } v; v.f = f;
  return (ushort_t)((v.u + 0x8000u) >> 16);
}
__device__ __forceinline__ float lk(float x) { return fmaxf(x, NS * x); }
__device__ __forceinline__ floatx2 lk2(floatx2 v) {
  return __builtin_elementwise_max(v, v * (floatx2){NS, NS});
}

// 16-lane-row full butterfly sum on the VALU pipe (DPP), zero LDS ops.
__device__ __forceinline__ float row16_sum(float x) {
  int t;
  t = __builtin_amdgcn_update_dpp(0, __builtin_bit_cast(int, x), 0x128, 0xF, 0xF, true); // row_ror:8
  x += __builtin_bit_cast(float, t);
  t = __builtin_amdgcn_update_dpp(0, __builtin_bit_cast(int, x), 0x124, 0xF, 0xF, true); // row_ror:4
  x += __builtin_bit_cast(float, t);
  t = __builtin_amdgcn_update_dpp(0, __builtin_bit_cast(int, x), 0x4E, 0xF, 0xF, true);  // quad xor2
  x += __builtin_bit_cast(float, t);
  t = __builtin_amdgcn_update_dpp(0, __builtin_bit_cast(int, x), 0xB1, 0xF, 0xF, true);  // quad xor1
  x += __builtin_bit_cast(float, t);
  return x;
}

// fragment-linear weight layout: element e = f*8+j, f = (s*NT + t)*64 + lane,
// value = W[k = s*32 + (lane>>4)*8 + j][n = t*16 + (lane&15)]  (W is KxN row-major)
__global__ __launch_bounds__(256) void prep_w(
    const float* __restrict__ W_e1, const float* __restrict__ W_e2,
    const float* __restrict__ W_h1, const float* __restrict__ W_h2,
    ushort_t* __restrict__ wijf, ushort_t* __restrict__ we2f,
    ushort_t* __restrict__ wh1f, ushort_t* __restrict__ wh2f) {
  int e = blockIdx.x * 256 + threadIdx.x;
  int which, le;
  if (e < 32768) { which = 0; le = e; }
  else if (e < 49152) { which = 1; le = e - 32768; }
  else if (e < 81920) { which = 2; le = e - 49152; }
  else { which = 3; le = e - 81920; }
  const int NT = (which == 0) ? 16 : 8;
  int f = le >> 3, j = le & 7;
  int lane = f & 63, ft = f >> 6;
  int t = ft % NT, s = ft / NT;
  int n = t * 16 + (lane & 15), k = s * 32 + (lane >> 4) * 8 + j;
  float v; ushort_t* d;
  if (which == 0) { v = (n < 128) ? W_e1[k * 128 + n] : W_e1[(128 + k) * 128 + (n - 128)]; d = wijf; }
  else if (which == 1) { v = W_e2[k * 128 + n]; d = we2f; }
  else if (which == 2) { v = W_h1[k * 128 + n]; d = wh1f; }
  else { v = W_h2[k * 128 + n]; d = wh2f; }
  d[le] = f2bf_rne(v);
}

// proj epilogue store: ti plain [m][n<128]; tj fragment-linear for the edge kernel:
// tjf[(((b*4 + s)*256 + j)*4 + lg)*8 + j8] = tj[j][k], k = s*32+lg*8+j8
__device__ __forceinline__ void proj_store(float v, int m, int n,
                                           float* __restrict__ ti, float* __restrict__ tjf) {
  if (n < 128) {
    ti[(size_t)m * 128 + n] = v;
  } else {
    int k = n - 128, b = m >> 8, j = m & 255;
    int s = k >> 5, lg2 = (k >> 3) & 3, j8 = k & 7;
    tjf[((((size_t)(b * 4 + s)) * 256 + j) * 4 + lg2) * 8 + j8] = v;
  }
}

// ---------------- h0 = leaky(fres @ W_emb) fused with proj [ti|tj] = h0 @ Wij ----------------
// 8 rows/block, 256 blocks. MFMA A rows 8-15 are stale LDS; A-row m only affects
// output row m, so all stores guarded to local row < 8.
__global__ __launch_bounds__(256) void h0_proj(
    const float* __restrict__ fres, const float* __restrict__ Wemb,
    const ushort_t* __restrict__ wijf, float* __restrict__ h_out,
    float* __restrict__ ti, float* __restrict__ tjf) {
  const int m0 = blockIdx.x * 8;
  const int tid = threadIdx.x;
  const int w = tid >> 6, lane = tid & 63, l16 = lane & 15, lg = lane >> 4;
  __shared__ __align__(16) ushort_t sH[16][136];   // rows 8-15 stale (never stored from)
  {
    const int row = tid >> 5, c0 = (tid & 31) * 4;
    const float* fr = fres + (size_t)(m0 + row) * 20;
    float a[4] = {0, 0, 0, 0};
    for (int k = 0; k < 20; ++k) {
      float fv = fr[k];
      float4 w0 = *(const float4*)(Wemb + k * 128 + c0);
      a[0] += fv * w0.x; a[1] += fv * w0.y; a[2] += fv * w0.z; a[3] += fv * w0.w;
    }
#pragma unroll
    for (int x = 0; x < 4; ++x) a[x] = lk(a[x]);
    float* ho = h_out + (size_t)(m0 + row) * 128 + c0;
    *(float4*)ho = (float4){a[0], a[1], a[2], a[3]};
    unsigned int* sh = (unsigned int*)&sH[row][c0];
    sh[0] = pk2bf(a[0], a[1]); sh[1] = pk2bf(a[2], a[3]);
  }
  __syncthreads();
  floatx4 ap[4];
#pragma unroll
  for (int q = 0; q < 4; ++q) ap[q] = (floatx4){0.f, 0.f, 0.f, 0.f};
  const shortx8* Wp = (const shortx8*)wijf;
#pragma unroll
  for (int s = 0; s < 4; ++s) {
    shortx8 af = *(const shortx8*)&sH[l16][s * 32 + lg * 8];
#pragma unroll
    for (int q = 0; q < 4; ++q)
      ap[q] = __builtin_amdgcn_mfma_f32_16x16x32_bf16(af, Wp[(s * 16 + 4 * w + q) * 64 + lane], ap[q], 0, 0, 0);
  }
#pragma unroll
  for (int q = 0; q < 4; ++q) {
    const int n = (4 * w + q) * 16 + l16;
#pragma unroll
    for (int r = 0; r < 4; ++r) {
      const int rl = lg * 4 + r;
      if (rl < 8) proj_store(ap[q][r], m0 + rl, n, ti, tjf);
    }
  }
}

// ---------------- edge kernel v9: dual-i + global_load_lds staging + XCD batch locality ----------------
// blk decode puts batch b = blk&7 -> (round-robin bid->XCD) each XCD serves one batch:
// its tjf slice (512KB)+We2+ti stay L2-resident. We2 staged direct-to-LDS (no ds_write).
__global__ __launch_bounds__(256, 2) void edge_kernel(
    const float* __restrict__ ti, const float* __restrict__ tjf,
    const float* __restrict__ coords, const ushort_t* __restrict__ we2f,
    const float* __restrict__ W_e1, const float* __restrict__ b_e1,
    const float* __restrict__ b_e2, const float* __restrict__ W_inf,
    const float* __restrict__ b_inf, float* __restrict__ mp0, float* __restrict__ mp1) {
  const int blk = blockIdx.x;                 // XCD-major decode: b in low bits
  const int b = blk & 7;
  const int ch = (blk >> 3) & 1;
  const int ip = blk >> 4;
  const int i0 = ip * 2;
  const int tid = threadIdx.x;
  const int w = tid >> 6, lane = tid & 63, l16 = lane & 15, lg = lane >> 4;

  __shared__ __align__(16) ushort_t sW[16384];   // 32 KB We2 fragment-linear
  __shared__ __align__(16) float sTiP[2][128];
  __shared__ __align__(16) float sWd[128];
  __shared__ __align__(16) float sD2[2][128];
  __shared__ __align__(16) float sMp[2][4][128];

  {
    // direct global->LDS staging: dest = wave-uniform base + lane*16 (linear)
    const int wbase = tid & ~63;   // w*64
#pragma unroll
    for (int r = 0; r < 8; ++r) {
      const ushort_t* g = we2f + (size_t)(r * 256 + tid) * 8;
      ushort_t* l = (ushort_t*)sW + (size_t)(r * 256 + wbase) * 8;
      __builtin_amdgcn_global_load_lds(g, l, 16, 0, 0);
    }
  }
  if (tid < 128) {
    sTiP[0][tid] = ti[(size_t)(b * 256 + i0) * 128 + tid] + b_e1[tid];
    sWd[tid] = W_e1[256 * 128 + tid];
  } else {
    const int t2 = tid - 128;
    sTiP[1][t2] = ti[(size_t)(b * 256 + i0 + 1) * 128 + t2] + b_e1[t2];
  }
  {
    const int ii = tid >> 7, jj = tid & 127;
    const int iv = i0 + ii, jv = ch * 128 + jj;
    float dx = coords[(size_t)(b * 256 + iv) * 3 + 0] - coords[(size_t)(b * 256 + jv) * 3 + 0];
    float dy = coords[(size_t)(b * 256 + iv) * 3 + 1] - coords[(size_t)(b * 256 + jv) * 3 + 1];
    float dz = coords[(size_t)(b * 256 + iv) * 3 + 2] - coords[(size_t)(b * 256 + jv) * 3 + 2];
    sD2[ii][jj] = dx * dx + dy * dy + dz * dz;
  }

  floatx4 acc[2][2][8];
#pragma unroll
  for (int t = 0; t < 8; ++t) {
    float bv = b_e2[t * 16 + l16];
    floatx4 v = (floatx4){bv, bv, bv, bv};
    acc[0][0][t] = v; acc[0][1][t] = v; acc[1][0][t] = v; acc[1][1][t] = v;
  }
  __syncthreads();

  float d2a[2][2];
#pragma unroll
  for (int ii = 0; ii < 2; ++ii)
#pragma unroll
    for (int c = 0; c < 2; ++c)
      d2a[ii][c] = sD2[ii][c * 64 + w * 16 + l16];
  const shortx8* sWf = (const shortx8*)sW;

#pragma unroll
  for (int s = 0; s < 4; ++s) {
    const int k0 = s * 32 + lg * 8;
    floatx2 w2[4];
#pragma unroll
    for (int x = 0; x < 4; ++x) w2[x] = *(const floatx2*)&sWd[k0 + 2 * x];
    shortx8 af[2][2];
#pragma unroll
    for (int c = 0; c < 2; ++c) {
      const int jr = ch * 128 + c * 64 + w * 16 + l16;   // j row (shared by both i)
      const float* tb = tjf + (((size_t)(b * 4 + s) * 256 + jr) * 4 + lg) * 8;
      float4 t0 = *(const float4*)tb;
      float4 t1 = *(const float4*)(tb + 4);
#pragma unroll
      for (int ii = 0; ii < 2; ++ii) {
        floatx2 p0 = *(const floatx2*)&sTiP[ii][k0 + 0];
        floatx2 p1 = *(const floatx2*)&sTiP[ii][k0 + 2];
        floatx2 p2v = *(const floatx2*)&sTiP[ii][k0 + 4];
        floatx2 p3 = *(const floatx2*)&sTiP[ii][k0 + 6];
        const floatx2 d2v = (floatx2){d2a[ii][c], d2a[ii][c]};
        floatx2 l0 = lk2((floatx2){t0.x, t0.y} + (p0 + d2v * w2[0]));
        floatx2 l1 = lk2((floatx2){t0.z, t0.w} + (p1 + d2v * w2[1]));
        floatx2 l2 = lk2((floatx2){t1.x, t1.y} + (p2v + d2v * w2[2]));
        floatx2 l3 = lk2((floatx2){t1.z, t1.w} + (p3 + d2v * w2[3]));
        union { shortx8 s8; unsigned int u[4]; } A;
        A.u[0] = cvtpk_bf16(l0.x, l0.y); A.u[1] = cvtpk_bf16(l1.x, l1.y);
        A.u[2] = cvtpk_bf16(l2.x, l2.y); A.u[3] = cvtpk_bf16(l3.x, l3.y);
        af[ii][c] = A.s8;
      }
    }
#pragma unroll
    for (int tg = 0; tg < 2; ++tg) {
      shortx8 b0 = sWf[(s * 8 + tg * 4 + 0) * 64 + lane];
      shortx8 b1 = sWf[(s * 8 + tg * 4 + 1) * 64 + lane];
      shortx8 b2 = sWf[(s * 8 + tg * 4 + 2) * 64 + lane];
      shortx8 b3 = sWf[(s * 8 + tg * 4 + 3) * 64 + lane];
      __builtin_amdgcn_s_setprio(1);
#pragma unroll
      for (int ii = 0; ii < 2; ++ii)
#pragma unroll
        for (int c = 0; c < 2; ++c) {
          acc[ii][c][tg * 4 + 0] = __builtin_amdgcn_mfma_f32_16x16x32_bf16(af[ii][c], b0, acc[ii][c][tg * 4 + 0], 0, 0, 0);
          acc[ii][c][tg * 4 + 1] = __builtin_amdgcn_mfma_f32_16x16x32_bf16(af[ii][c], b1, acc[ii][c][tg * 4 + 1], 0, 0, 0);
          acc[ii][c][tg * 4 + 2] = __builtin_amdgcn_mfma_f32_16x16x32_bf16(af[ii][c], b2, acc[ii][c][tg * 4 + 2], 0, 0, 0);
          acc[ii][c][tg * 4 + 3] = __builtin_amdgcn_mfma_f32_16x16x32_bf16(af[ii][c], b3, acc[ii][c][tg * 4 + 3], 0, 0, 0);
        }
      __builtin_amdgcn_s_setprio(0);
    }
  }

  // epilogue per i: leaky, gate, masked weighted reduction (DPP row-reduce)
  float winfv[8];
#pragma unroll
  for (int t = 0; t < 8; ++t) winfv[t] = W_inf[t * 16 + l16];
  const float binf = b_inf[0];
#pragma unroll
  for (int ii = 0; ii < 2; ++ii) {
    const int i = i0 + ii;
    float mpacc[8];
#pragma unroll
    for (int t = 0; t < 8; ++t) mpacc[t] = 0.f;
#pragma unroll
    for (int c = 0; c < 2; ++c) {
#pragma unroll
      for (int t = 0; t < 8; ++t) {
        floatx2 v0 = lk2((floatx2){acc[ii][c][t][0], acc[ii][c][t][1]});
        floatx2 v1 = lk2((floatx2){acc[ii][c][t][2], acc[ii][c][t][3]});
        acc[ii][c][t][0] = v0.x; acc[ii][c][t][1] = v0.y;
        acc[ii][c][t][2] = v1.x; acc[ii][c][t][3] = v1.y;
      }
#pragma unroll
      for (int r = 0; r < 4; ++r) {
        float sum = 0.f;
#pragma unroll
        for (int t = 0; t < 8; ++t) sum += acc[ii][c][t][r] * winfv[t];
        sum = row16_sum(sum);
        const int jg = ch * 128 + c * 64 + w * 16 + lg * 4 + r;
        float x = sum + binf;
        float e = __builtin_amdgcn_rcpf(1.f + __expf(-x));
        if (jg == i) e = 0.f;
#pragma unroll
        for (int t = 0; t < 8; ++t) mpacc[t] += acc[ii][c][t][r] * e;
      }
    }
#pragma unroll
    for (int t = 0; t < 8; ++t) {
      mpacc[t] += __shfl_xor(mpacc[t], 16);
      mpacc[t] += __shfl_xor(mpacc[t], 32);
    }
    if (lg == 0) {
#pragma unroll
      for (int t = 0; t < 8; ++t) sMp[ii][w][t * 16 + l16] = mpacc[t];
    }
  }
  __syncthreads();
  {
    const int ii = tid >> 7, col = tid & 127;
    float v = sMp[ii][0][col] + sMp[ii][1][col] + sMp[ii][2][col] + sMp[ii][3][col];
    float* mpo = ch ? mp1 : mp0;
    mpo[(size_t)(b * 256 + i0 + ii) * 128 + col] = v;
  }
}

// ---------------- fused node MLP (+ next-iteration proj) ----------------
// 8 rows/block, 256 blocks. Stale LDS rows 8-15 only affect unstored output
// rows (MFMA A-row m -> D-row m); all stores guarded to local row < 8.
__global__ __launch_bounds__(256) void node_kernel(
    const float* __restrict__ h_in, const float* __restrict__ mp0, const float* __restrict__ mp1,
    const ushort_t* __restrict__ wh1f, const float* __restrict__ b_h1,
    const ushort_t* __restrict__ wh2f, const float* __restrict__ b_h2,
    const ushort_t* __restrict__ wijf, float* __restrict__ h_out,
    float* __restrict__ ti, float* __restrict__ tjf, const int do_proj) {
  const int m0 = blockIdx.x * 8;
  const int tid = threadIdx.x;
  const int w = tid >> 6, lane = tid & 63, l16 = lane & 15, lg = lane >> 4;
  __shared__ __align__(16) ushort_t sA[16][264];
  __shared__ __align__(16) ushort_t sU[16][136];
  __shared__ __align__(16) ushort_t sHp[16][136];

  {
    const int row = tid >> 5, c0 = (tid & 31) * 8;
    unsigned int* dst = (unsigned int*)&sA[row][c0];
    if (c0 < 128) {
      const float* src = h_in + (size_t)(m0 + row) * 128 + c0;
#pragma unroll
      for (int x = 0; x < 4; ++x) dst[x] = pk2bf(src[2 * x], src[2 * x + 1]);
    } else {
      const float* s0 = mp0 + (size_t)(m0 + row) * 128 + (c0 - 128);
      const float* s1 = mp1 + (size_t)(m0 + row) * 128 + (c0 - 128);
#pragma unroll
      for (int x = 0; x < 4; ++x)
        dst[x] = pk2bf(s0[2 * x] + s1[2 * x], s0[2 * x + 1] + s1[2 * x + 1]);
    }
  }
  __syncthreads();
  // u tiles {2w, 2w+1}
  floatx4 au[2];
#pragma unroll
  for (int q = 0; q < 2; ++q) { float bv = b_h1[(2 * w + q) * 16 + l16]; au[q] = (floatx4){bv, bv, bv, bv}; }
  const shortx8* W1 = (const shortx8*)wh1f;
#pragma unroll
  for (int s = 0; s < 8; ++s) {
    shortx8 af = *(const shortx8*)&sA[l16][s * 32 + lg * 8];
#pragma unroll
    for (int q = 0; q < 2; ++q)
      au[q] = __builtin_amdgcn_mfma_f32_16x16x32_bf16(af, W1[(s * 8 + 2 * w + q) * 64 + lane], au[q], 0, 0, 0);
  }
#pragma unroll
  for (int q = 0; q < 2; ++q)
#pragma unroll
    for (int r = 0; r < 4; ++r) {
      const int rl = lg * 4 + r;
      if (rl < 8) sU[rl][(2 * w + q) * 16 + l16] = f2bf_rhu(lk(au[q][r]));
    }
  __syncthreads();
  // h' tiles {2w, 2w+1}
  floatx4 ah[2];
#pragma unroll
  for (int q = 0; q < 2; ++q) { float bv = b_h2[(2 * w + q) * 16 + l16]; ah[q] = (floatx4){bv, bv, bv, bv}; }
  const shortx8* W2 = (const shortx8*)wh2f;
#pragma unroll
  for (int s = 0; s < 4; ++s) {
    shortx8 af = *(const shortx8*)&sU[l16][s * 32 + lg * 8];
#pragma unroll
    for (int q = 0; q < 2; ++q)
      ah[q] = __builtin_amdgcn_mfma_f32_16x16x32_bf16(af, W2[(s * 8 + 2 * w + q) * 64 + lane], ah[q], 0, 0, 0);
  }
#pragma unroll
  for (int q = 0; q < 2; ++q) {
    const int n = (2 * w + q) * 16 + l16;
#pragma unroll
    for (int r = 0; r < 4; ++r) {
      const int rl = lg * 4 + r;
      if (rl < 8) {
        const int m = m0 + rl;
        float v = ah[q][r] + h_in[(size_t)m * 128 + n];
        h_out[(size_t)m * 128 + n] = v;
        sHp[rl][n] = f2bf_rhu(v);
      }
    }
  }
  if (!do_proj) return;
  __syncthreads();
  // proj tiles {4w..4w+3}
  floatx4 ap[4];
#pragma unroll
  for (int q = 0; q < 4; ++q) ap[q] = (floatx4){0.f, 0.f, 0.f, 0.f};
  const shortx8* Wp = (const shortx8*)wijf;
#pragma unroll
  for (int s = 0; s < 4; ++s) {
    shortx8 af = *(const shortx8*)&sHp[l16][s * 32 + lg * 8];
#pragma unroll
    for (int q = 0; q < 4; ++q)
      ap[q] = __builtin_amdgcn_mfma_f32_16x16x32_bf16(af, Wp[(s * 16 + 4 * w + q) * 64 + lane], ap[q], 0, 0, 0);
  }
#pragma unroll
  for (int q = 0; q < 4; ++q) {
    const int n = (4 * w + q) * 16 + l16;
#pragma unroll
    for (int r = 0; r < 4; ++r) {
      const int rl = lg * 4 + r;
      if (rl < 8) proj_store(ap[q][r], m0 + rl, n, ti, tjf);
    }
  }
}

extern "C" void kernel_launch(void* const* d_in, const int* in_sizes, int n_in,
                              void* d_out, int out_size, void* d_ws, size_t ws_size,
                              hipStream_t stream) {
  const float* fres   = (const float*)d_in[0];
  const float* coords = (const float*)d_in[1];
  const float* W_emb  = (const float*)d_in[2];
  const float* W_e1   = (const float*)d_in[3];
  const float* b_e1   = (const float*)d_in[4];
  const float* W_e2   = (const float*)d_in[5];
  const float* b_e2   = (const float*)d_in[6];
  const float* W_inf  = (const float*)d_in[7];
  const float* b_inf  = (const float*)d_in[8];
  const float* W_h1   = (const float*)d_in[9];
  const float* b_h1   = (const float*)d_in[10];
  const float* W_h2   = (const float*)d_in[11];
  const float* b_h2   = (const float*)d_in[12];
  float* out = (float*)d_out;

  char* ws = (char*)d_ws;
  float* hA  = (float*)(ws + (0 << 20));
  float* hB  = (float*)(ws + (1 << 20));
  float* tib = (float*)(ws + (2 << 20));
  float* tjf = (float*)(ws + (3 << 20));
  float* mp0 = (float*)(ws + (4 << 20));
  float* mp1 = (float*)(ws + (5 << 20));
  ushort_t* wijf = (ushort_t*)(ws + (6 << 20));
  ushort_t* we2f = wijf + 32768;
  ushort_t* wh1f = we2f + 16384;
  ushort_t* wh2f = wh1f + 32768;

  prep_w<<<384, 256, 0, stream>>>(W_e1, W_e2, W_h1, W_h2, wijf, we2f, wh1f, wh2f);
  h0_proj<<<256, 256, 0, stream>>>(fres, W_emb, wijf, hA, tib, tjf);

  edge_kernel<<<2048, 256, 0, stream>>>(tib, tjf, coords, we2f, W_e1, b_e1, b_e2, W_inf, b_inf, mp0, mp1);
  node_kernel<<<256, 256, 0, stream>>>(hA, mp0, mp1, wh1f, b_h1, wh2f, b_h2, wijf, hB, tib, tjf, 1);

  edge_kernel<<<2048, 256, 0, stream>>>(tib, tjf, coords, we2f, W_e1, b_e1, b_e2, W_inf, b_inf, mp0, mp1);
  node_kernel<<<256, 256, 0, stream>>>(hB, mp0, mp1, wh1f, b_h1, wh2f, b_h2, wijf, out, tib, tjf, 0);
}